// Round 1
// baseline (68.566 us; speedup 1.0000x reference)
//
#include <hip/hip_runtime.h>
#include <hip/hip_bf16.h>

// out[s,o] = sum_k x[s,k]*W[o,k]  (bf16 MFMA)
//          + zc_w*8*sum_r A[o,r]*t[r,s] + zc_b*xsum[s] + bias[o]   (fp32 exact)
// t[r,s] = sum_k B[r,k]*x[s,k],  xsum[s] = sum_k x[s,k]

typedef __attribute__((ext_vector_type(8))) short bf16x8;
typedef __attribute__((ext_vector_type(4))) float f32x4;

#define MDIM 512
#define NDIM 4096
#define KDIM 4096
#define BM 64
#define BN 128
#define BK 64
#define NT (KDIM / BK)   // 64 K-tiles

static __device__ inline unsigned short f2bf(float f) {
  union { float f; unsigned u; } c; c.f = f;
  unsigned u = c.u;
  unsigned r = u + 0x7FFFu + ((u >> 16) & 1u);  // round-to-nearest-even
  return (unsigned short)(r >> 16);
}

static __device__ inline void cvt_store16(unsigned short* dst, f32x4 a, f32x4 b) {
  bf16x8 v;
  v[0] = (short)f2bf(a[0]); v[1] = (short)f2bf(a[1]);
  v[2] = (short)f2bf(a[2]); v[3] = (short)f2bf(a[3]);
  v[4] = (short)f2bf(b[0]); v[5] = (short)f2bf(b[1]);
  v[6] = (short)f2bf(b[2]); v[7] = (short)f2bf(b[3]);
  *(bf16x8*)dst = v;
}

// ---------------- t / xsum kernel ----------------
__global__ __launch_bounds__(256) void tk_kernel(
    const float* __restrict__ x, const float* __restrict__ B,
    float* __restrict__ t, float* __restrict__ xs) {
  int s = blockIdx.x;
  int tid = threadIdx.x;
  const float* xr = x + (long)s * KDIM;
  float a0 = 0.f, a1 = 0.f, a2 = 0.f, a3 = 0.f, a4 = 0.f;
  for (int k = tid * 4; k < KDIM; k += 1024) {
    f32x4 xv = *(const f32x4*)&xr[k];
    f32x4 b0 = *(const f32x4*)&B[0 * KDIM + k];
    f32x4 b1 = *(const f32x4*)&B[1 * KDIM + k];
    f32x4 b2 = *(const f32x4*)&B[2 * KDIM + k];
    f32x4 b3 = *(const f32x4*)&B[3 * KDIM + k];
    a0 += xv[0]*b0[0] + xv[1]*b0[1] + xv[2]*b0[2] + xv[3]*b0[3];
    a1 += xv[0]*b1[0] + xv[1]*b1[1] + xv[2]*b1[2] + xv[3]*b1[3];
    a2 += xv[0]*b2[0] + xv[1]*b2[1] + xv[2]*b2[2] + xv[3]*b2[3];
    a3 += xv[0]*b3[0] + xv[1]*b3[1] + xv[2]*b3[2] + xv[3]*b3[3];
    a4 += xv[0] + xv[1] + xv[2] + xv[3];
  }
  #pragma unroll
  for (int off = 32; off; off >>= 1) {
    a0 += __shfl_down(a0, off, 64);
    a1 += __shfl_down(a1, off, 64);
    a2 += __shfl_down(a2, off, 64);
    a3 += __shfl_down(a3, off, 64);
    a4 += __shfl_down(a4, off, 64);
  }
  __shared__ float red[4][5];
  int w = tid >> 6, l = tid & 63;
  if (l == 0) { red[w][0]=a0; red[w][1]=a1; red[w][2]=a2; red[w][3]=a3; red[w][4]=a4; }
  __syncthreads();
  if (tid == 0) {
    t[0 * MDIM + s] = red[0][0] + red[1][0] + red[2][0] + red[3][0];
    t[1 * MDIM + s] = red[0][1] + red[1][1] + red[2][1] + red[3][1];
    t[2 * MDIM + s] = red[0][2] + red[1][2] + red[2][2] + red[3][2];
    t[3 * MDIM + s] = red[0][3] + red[1][3] + red[2][3] + red[3][3];
    xs[s]           = red[0][4] + red[1][4] + red[2][4] + red[3][4];
  }
}

// ---------------- main GEMM + epilogue ----------------
__global__ __launch_bounds__(512) void gemm_kernel(
    const float* __restrict__ x, const float* __restrict__ W,
    const float* __restrict__ A, const float* __restrict__ bias,
    const float* __restrict__ zcw, const float* __restrict__ zcb,
    const float* __restrict__ t, const float* __restrict__ xs,
    float* __restrict__ out) {
  __shared__ __align__(16) unsigned short As[2][BM * BK];
  __shared__ __align__(16) unsigned short Ws[2][BN * BK];

  const int bid = blockIdx.x;
  const int bn = bid % (NDIM / BN);   // 32
  const int bm = bid / (NDIM / BN);   // 8
  const int tid = threadIdx.x;
  const int lane = tid & 63;
  const int wid = tid >> 6;           // 0..7
  const int wm = wid >> 2;            // 0..1
  const int wn = wid & 3;             // 0..3

  // staging map: thread -> (row, 8-float chunk)
  const int srow = tid >> 3;          // 0..63
  const int skc = (tid & 7) * 8;      // 0,8,...,56
  const float* xg  = x + (long)(bm * BM + srow) * KDIM + skc;
  const float* wg0 = W + (long)(bn * BN + srow) * KDIM + skc;
  const float* wg1 = W + (long)(bn * BN + srow + 64) * KDIM + skc;
  const int aoff  = (srow * BK + skc) ^ ((srow & 7) << 3);
  const int woff0 = aoff;
  const int woff1 = ((srow + 64) * BK + skc) ^ ((srow & 7) << 3);

  // fragment read map
  const int fr = lane & 15;
  const int fk = (lane >> 4) * 8;

  f32x4 acc[2][2] = {};
  f32x4 xv0, xv1, wv0, wv1, wv2, wv3;

  // prologue: load + stage tile 0
  xv0 = *(const f32x4*)(xg);      xv1 = *(const f32x4*)(xg + 4);
  wv0 = *(const f32x4*)(wg0);     wv1 = *(const f32x4*)(wg0 + 4);
  wv2 = *(const f32x4*)(wg1);     wv3 = *(const f32x4*)(wg1 + 4);
  cvt_store16(&As[0][aoff], xv0, xv1);
  cvt_store16(&Ws[0][woff0], wv0, wv1);
  cvt_store16(&Ws[0][woff1], wv2, wv3);
  __syncthreads();

  for (int kt = 0; kt < NT; ++kt) {
    const int cur = kt & 1;
    if (kt + 1 < NT) {
      const int off = (kt + 1) * BK;
      xv0 = *(const f32x4*)(xg + off);      xv1 = *(const f32x4*)(xg + off + 4);
      wv0 = *(const f32x4*)(wg0 + off);     wv1 = *(const f32x4*)(wg0 + off + 4);
      wv2 = *(const f32x4*)(wg1 + off);     wv3 = *(const f32x4*)(wg1 + off + 4);
    }
    #pragma unroll
    for (int ks = 0; ks < 2; ++ks) {
      const int kk = ks * 32 + fk;
      const int ra0 = wm * 32 + fr;
      const int ra1 = wm * 32 + 16 + fr;
      const int rb0 = wn * 32 + fr;
      const int rb1 = wn * 32 + 16 + fr;
      bf16x8 a0 = *(const bf16x8*)&As[cur][(ra0 * BK + kk) ^ ((ra0 & 7) << 3)];
      bf16x8 a1 = *(const bf16x8*)&As[cur][(ra1 * BK + kk) ^ ((ra1 & 7) << 3)];
      bf16x8 b0 = *(const bf16x8*)&Ws[cur][(rb0 * BK + kk) ^ ((rb0 & 7) << 3)];
      bf16x8 b1 = *(const bf16x8*)&Ws[cur][(rb1 * BK + kk) ^ ((rb1 & 7) << 3)];
      acc[0][0] = __builtin_amdgcn_mfma_f32_16x16x32_bf16(a0, b0, acc[0][0], 0, 0, 0);
      acc[0][1] = __builtin_amdgcn_mfma_f32_16x16x32_bf16(a0, b1, acc[0][1], 0, 0, 0);
      acc[1][0] = __builtin_amdgcn_mfma_f32_16x16x32_bf16(a1, b0, acc[1][0], 0, 0, 0);
      acc[1][1] = __builtin_amdgcn_mfma_f32_16x16x32_bf16(a1, b1, acc[1][1], 0, 0, 0);
    }
    if (kt + 1 < NT) {
      const int nxt = cur ^ 1;
      cvt_store16(&As[nxt][aoff], xv0, xv1);
      cvt_store16(&Ws[nxt][woff0], wv0, wv1);
      cvt_store16(&Ws[nxt][woff1], wv2, wv3);
    }
    __syncthreads();
  }

  // epilogue: exact fp32 low-rank correction + bias
  const float zw8 = zcw[0] * 8.0f;
  const float zb = zcb[0];
  const int s0 = bm * BM + wm * 32;
  const int o0 = bn * BN + wn * 32;
  #pragma unroll
  for (int mi = 0; mi < 2; ++mi) {
    const int sb = s0 + mi * 16 + ((lane >> 4) * 4);
    f32x4 t0 = *(const f32x4*)&t[0 * MDIM + sb];
    f32x4 t1 = *(const f32x4*)&t[1 * MDIM + sb];
    f32x4 t2 = *(const f32x4*)&t[2 * MDIM + sb];
    f32x4 t3 = *(const f32x4*)&t[3 * MDIM + sb];
    f32x4 x4 = *(const f32x4*)&xs[sb];
    #pragma unroll
    for (int ni = 0; ni < 2; ++ni) {
      const int o = o0 + ni * 16 + fr;
      f32x4 a4 = *(const f32x4*)&A[o * 4];
      const float bo = bias[o];
      #pragma unroll
      for (int j = 0; j < 4; ++j) {
        float corr = zw8 * (a4[0] * t0[j] + a4[1] * t1[j] + a4[2] * t2[j] + a4[3] * t3[j])
                   + zb * x4[j] + bo;
        out[(long)(sb + j) * NDIM + o] = acc[mi][ni][j] + corr;
      }
    }
  }
}

extern "C" void kernel_launch(void* const* d_in, const int* in_sizes, int n_in,
                              void* d_out, int out_size, void* d_ws, size_t ws_size,
                              hipStream_t stream) {
  const float* x    = (const float*)d_in[0];
  const float* W    = (const float*)d_in[1];
  const float* A    = (const float*)d_in[2];
  const float* B    = (const float*)d_in[3];
  const float* zcw  = (const float*)d_in[4];
  const float* zcb  = (const float*)d_in[5];
  const float* bias = (const float*)d_in[6];
  float* out = (float*)d_out;

  float* t  = (float*)d_ws;           // [4][512]
  float* xs = t + 4 * MDIM;           // [512]

  tk_kernel<<<MDIM, 256, 0, stream>>>(x, B, t, xs);
  gemm_kernel<<<(MDIM / BM) * (NDIM / BN), 512, 0, stream>>>(
      x, W, A, bias, zcw, zcb, t, xs, out);
}